// Round 1
// baseline (50.083 us; speedup 1.0000x reference)
//
#include <hip/hip_runtime.h>
#include <hip/hip_bf16.h>

// per-sample L1 loss (mean over D=16 features), weighted by (1 + 0.1*x[:,3]),
// mean over batch B. Memory-bound: 160 MB read, one scalar out.
//
// Layout trick: treat out/target as flat float4 arrays (B*16/4 elements).
// Each thread processes one float4 (a quarter of a row) -> perfectly
// coalesced 16B/lane loads. Weight lookup x[row*8+3] is broadcast-shared by
// the 4 threads covering a row (reads land in L1/L2 lines anyway).

__global__ void weighted_l1_loss_kernel(const float4* __restrict__ outp,
                                        const float4* __restrict__ tgtp,
                                        const float* __restrict__ x,
                                        float* __restrict__ res,
                                        int n4, float inv_scale) {
    float acc = 0.0f;
    int idx = blockIdx.x * blockDim.x + threadIdx.x;
    int stride = gridDim.x * blockDim.x;
    for (int q = idx; q < n4; q += stride) {
        float4 a = outp[q];
        float4 b = tgtp[q];
        float s = fabsf(a.x - b.x) + fabsf(a.y - b.y)
                + fabsf(a.z - b.z) + fabsf(a.w - b.w);
        int row = q >> 2;                      // 4 float4 per row of 16
        float w = 1.0f + 0.1f * x[row * 8 + 3];
        acc += s * w;
    }
    acc *= inv_scale;  // 1/(16*B): fold both means into one scale

    // wave-64 butterfly reduce
    #pragma unroll
    for (int off = 32; off > 0; off >>= 1)
        acc += __shfl_down(acc, off);

    __shared__ float wsum[4];  // 256 threads = 4 waves
    int lane = threadIdx.x & 63;
    int wid  = threadIdx.x >> 6;
    if (lane == 0) wsum[wid] = acc;
    __syncthreads();
    if (threadIdx.x == 0) {
        float t = wsum[0] + wsum[1] + wsum[2] + wsum[3];
        atomicAdd(res, t);  // device-scope by default (cross-XCD safe)
    }
}

extern "C" void kernel_launch(void* const* d_in, const int* in_sizes, int n_in,
                              void* d_out, int out_size, void* d_ws, size_t ws_size,
                              hipStream_t stream) {
    const float* outp = (const float*)d_in[0];  // [B,16]
    const float* tgtp = (const float*)d_in[1];  // [B,16]
    const float* x    = (const float*)d_in[2];  // [B,8]
    float* res = (float*)d_out;

    int B  = in_sizes[0] / 16;
    int n4 = B * 4;  // number of float4 chunks in out/target

    // harness poisons d_out once and never re-poisons between replays:
    // zero it every launch (async memset is graph-capture safe).
    hipMemsetAsync(d_out, 0, sizeof(float), stream);

    int block = 256;
    int grid  = (n4 + block - 1) / block;
    if (grid > 2048) grid = 2048;  // grid-stride the rest (G11)

    weighted_l1_loss_kernel<<<grid, block, 0, stream>>>(
        (const float4*)outp, (const float4*)tgtp, x, res,
        n4, 1.0f / (16.0f * (float)B));
}